// Round 1
// baseline (930.623 us; speedup 1.0000x reference)
//
#include <hip/hip_runtime.h>

// Problem constants
#define M_TOK 16384          // B*T = 8*2048
#define D_DIM 768
#define K_CB  2048

// GEMM tiling
#define TM 128               // token tile
#define TK 128               // code tile
#define DC 16                // depth chunk
#define KSPLIT 2
#define KRANGE (K_CB / KSPLIT)   // 1024 codes per block

// ---------------------------------------------------------------------------
// Kernel 1: e_sq[k] = sum_d codebook[k][d]^2.  One wave per code.
// ---------------------------------------------------------------------------
__global__ void vq_esq(const float* __restrict__ codebook, float* __restrict__ esq) {
    const int wid  = threadIdx.x >> 6;
    const int lane = threadIdx.x & 63;
    const int k = blockIdx.x * 4 + wid;
    const float* row = codebook + (size_t)k * D_DIM;
    float s = 0.f;
    #pragma unroll
    for (int j = lane; j < D_DIM; j += 64) {
        float v = row[j];
        s = fmaf(v, v, s);
    }
    #pragma unroll
    for (int off = 32; off; off >>= 1) s += __shfl_down(s, off);
    if (lane == 0) esq[k] = s;
}

// ---------------------------------------------------------------------------
// Kernel 2: distance GEMM + per-token argmin.
// Block: 256 threads (16x16). Tile TM=128 tokens x TK=128 codes, 8x8/thread.
// Each block covers KRANGE codes; global merge via atomicMin on packed key.
// dist_for_argmin = e_sq[k] - 2*dot  (x_sq dropped: constant per token).
// ---------------------------------------------------------------------------
__device__ __forceinline__ unsigned long long packKey(float s, int k) {
    unsigned u = __float_as_uint(s);
    u = (u & 0x80000000u) ? ~u : (u | 0x80000000u);  // monotone float->uint
    return ((unsigned long long)u << 32) | (unsigned)k;
}

__launch_bounds__(256, 1)
__global__ void vq_dist(const float* __restrict__ token,
                        const float* __restrict__ codebook,
                        const float* __restrict__ esq,
                        unsigned long long* __restrict__ packed) {
    __shared__ float As[DC][TM];        // token chunk, [d][tok]
    __shared__ float Bs[DC][TK];        // codebook chunk, [d][code]
    __shared__ float esq_s[KRANGE];

    const int tid = threadIdx.x;
    const int ty  = tid >> 4;           // 0..15
    const int tx  = tid & 15;           // 0..15
    const int tokBase = blockIdx.x * TM;
    const int kBase   = blockIdx.y * KRANGE;

    for (int j = tid; j < KRANGE; j += 256) esq_s[j] = esq[kBase + j];

    float runv[8];
    int   runk[8];
    #pragma unroll
    for (int i = 0; i < 8; ++i) { runv[i] = 3.4e38f; runk[i] = 0; }

    // Staging layout: thread loads row lr, cols lc..lc+7 (two float4)
    const int lr = tid >> 1;            // 0..127
    const int lc = (tid & 1) * 8;       // 0 or 8

    const float* tokPtr = token + (size_t)(tokBase + lr) * D_DIM + lc;

    for (int kt = 0; kt < KRANGE; kt += TK) {
        const float* cbPtr = codebook + (size_t)(kBase + kt + lr) * D_DIM + lc;

        float acc[8][8];
        #pragma unroll
        for (int i = 0; i < 8; ++i)
            #pragma unroll
            for (int j = 0; j < 8; ++j) acc[i][j] = 0.f;

        // prefetch chunk 0
        float4 pa0 = *(const float4*)(tokPtr + 0);
        float4 pa1 = *(const float4*)(tokPtr + 4);
        float4 pb0 = *(const float4*)(cbPtr + 0);
        float4 pb1 = *(const float4*)(cbPtr + 4);

        for (int dc = 0; dc < D_DIM; dc += DC) {
            __syncthreads();
            As[lc + 0][lr] = pa0.x; As[lc + 1][lr] = pa0.y;
            As[lc + 2][lr] = pa0.z; As[lc + 3][lr] = pa0.w;
            As[lc + 4][lr] = pa1.x; As[lc + 5][lr] = pa1.y;
            As[lc + 6][lr] = pa1.z; As[lc + 7][lr] = pa1.w;
            Bs[lc + 0][lr] = pb0.x; Bs[lc + 1][lr] = pb0.y;
            Bs[lc + 2][lr] = pb0.z; Bs[lc + 3][lr] = pb0.w;
            Bs[lc + 4][lr] = pb1.x; Bs[lc + 5][lr] = pb1.y;
            Bs[lc + 6][lr] = pb1.z; Bs[lc + 7][lr] = pb1.w;
            __syncthreads();

            // prefetch next chunk (overlaps with compute below)
            if (dc + DC < D_DIM) {
                pa0 = *(const float4*)(tokPtr + dc + DC + 0);
                pa1 = *(const float4*)(tokPtr + dc + DC + 4);
                pb0 = *(const float4*)(cbPtr + dc + DC + 0);
                pb1 = *(const float4*)(cbPtr + dc + DC + 4);
            }

            #pragma unroll
            for (int d = 0; d < DC; ++d) {
                const float4 a0 = *(const float4*)&As[d][ty * 4];
                const float4 a1 = *(const float4*)&As[d][64 + ty * 4];
                const float4 b0 = *(const float4*)&Bs[d][tx * 4];
                const float4 b1 = *(const float4*)&Bs[d][64 + tx * 4];
                float a[8] = {a0.x, a0.y, a0.z, a0.w, a1.x, a1.y, a1.z, a1.w};
                float b[8] = {b0.x, b0.y, b0.z, b0.w, b1.x, b1.y, b1.z, b1.w};
                #pragma unroll
                for (int i = 0; i < 8; ++i)
                    #pragma unroll
                    for (int j = 0; j < 8; ++j)
                        acc[i][j] = fmaf(a[i], b[j], acc[i][j]);
            }
        }

        // epilogue: per-token best over this code tile
        #pragma unroll
        for (int i = 0; i < 8; ++i) {
            float bv = 3.4e38f;
            int   bk = 0x7fffffff;
            #pragma unroll
            for (int j = 0; j < 8; ++j) {
                const int cj = (j < 4) ? (tx * 4 + j) : (64 + tx * 4 + (j - 4));
                const float s = esq_s[kt + cj] - 2.0f * acc[i][j];
                const int k = kBase + kt + cj;
                if (s < bv) { bv = s; bk = k; }   // ascending k: strict < keeps first
            }
            // reduce across the 16 tx lanes (same ty => same token rows)
            #pragma unroll
            for (int off = 1; off < 16; off <<= 1) {
                const float ov = __shfl_xor(bv, off);
                const int   ok = __shfl_xor(bk, off);
                if (ov < bv || (ov == bv && ok < bk)) { bv = ov; bk = ok; }
            }
            if (bv < runv[i]) { runv[i] = bv; runk[i] = bk; }  // ascending kt
        }
    }

    if (tx == 0) {
        #pragma unroll
        for (int i = 0; i < 8; ++i) {
            const int r = (i < 4) ? (ty * 4 + i) : (64 + ty * 4 + (i - 4));
            atomicMin(&packed[tokBase + r], packKey(runv[i], runk[i]));
        }
    }
}

// ---------------------------------------------------------------------------
// Kernel 3: finalize — gather quantized rows, write indices (as float),
// accumulate commit loss (mean squared diff).
// ---------------------------------------------------------------------------
__global__ void vq_finalize(const float* __restrict__ token,
                            const float* __restrict__ codebook,
                            const unsigned long long* __restrict__ packed,
                            float* __restrict__ out_q,
                            float* __restrict__ out_idx,
                            float* __restrict__ out_loss) {
    const int gid = blockIdx.x * blockDim.x + threadIdx.x;
    const int nthreads = gridDim.x * blockDim.x;
    const int N4 = (M_TOK * D_DIM) / 4;   // 3145728 float4s, 192 per row
    float lsum = 0.f;
    for (int i = gid; i < N4; i += nthreads) {
        const int t  = i / 192;
        const int c4 = (i - t * 192) * 4;
        const int idx = (int)(packed[t] & 0xFFFFFFFFull);
        const float4 q = *(const float4*)(codebook + (size_t)idx * D_DIM + c4);
        const float4 x = *(const float4*)(token + (size_t)t * D_DIM + c4);
        const float dx = q.x - x.x, dy = q.y - x.y, dz = q.z - x.z, dw = q.w - x.w;
        lsum += dx * dx + dy * dy + dz * dz + dw * dw;
        *(float4*)(out_q + (size_t)t * D_DIM + c4) = q;
    }
    if (gid < M_TOK) out_idx[gid] = (float)(packed[gid] & 0xFFFFFFFFull);

    #pragma unroll
    for (int off = 32; off; off >>= 1) lsum += __shfl_down(lsum, off);
    __shared__ float ws[4];
    const int lane = threadIdx.x & 63, wid = threadIdx.x >> 6;
    if (lane == 0) ws[wid] = lsum;
    __syncthreads();
    if (threadIdx.x == 0)
        atomicAdd(out_loss, (ws[0] + ws[1] + ws[2] + ws[3]) *
                            (1.0f / (float)((size_t)M_TOK * D_DIM)));
}

// ---------------------------------------------------------------------------
extern "C" void kernel_launch(void* const* d_in, const int* in_sizes, int n_in,
                              void* d_out, int out_size, void* d_ws, size_t ws_size,
                              hipStream_t stream) {
    const float* token    = (const float*)d_in[0];
    const float* codebook = (const float*)d_in[1];

    float* out_q    = (float*)d_out;                       // 12,582,912 floats
    float* out_idx  = out_q + (size_t)M_TOK * D_DIM;       // 16,384 floats
    float* out_loss = out_idx + M_TOK;                     // 1 float

    // workspace: esq (2048 f32, 8 KiB) | packed argmin keys (16384 u64, 128 KiB)
    float* esq = (float*)d_ws;
    unsigned long long* packed = (unsigned long long*)((char*)d_ws + 8192);

    hipMemsetAsync(packed, 0xFF, (size_t)M_TOK * sizeof(unsigned long long), stream);
    hipMemsetAsync(out_loss, 0, sizeof(float), stream);

    vq_esq<<<K_CB / 4, 256, 0, stream>>>(codebook, esq);

    dim3 grid(M_TOK / TM, KSPLIT);
    vq_dist<<<grid, 256, 0, stream>>>(token, codebook, esq, packed);

    vq_finalize<<<2048, 256, 0, stream>>>(token, codebook, packed,
                                          out_q, out_idx, out_loss);
}

// Round 2
// 315.036 us; speedup vs baseline: 2.9540x; 2.9540x over previous
//
#include <hip/hip_runtime.h>

#define M_TOK 16384          // B*T
#define D_DIM 768
#define K_CB  2048

#define BTOK  128            // token tile
#define BCODE 128            // code tile
#define BK    32             // K chunk (one mfma k=32)
#define KSPLIT 4
#define SLICE (K_CB / KSPLIT)   // 512 codes per block
#define NCT   (SLICE / BCODE)   // 4 code tiles per block
#define NSLOT (KSPLIT * 2)      // per-token top2 slots (slice x code-half)
#define EPS   0.25f             // rescore margin (worst-case approx err ~0.07)

typedef __attribute__((ext_vector_type(8))) short bf16x8;
typedef __attribute__((ext_vector_type(4))) float f32x4;

__device__ __forceinline__ unsigned short f2bf(float x) {   // RNE f32->bf16
    unsigned u = __float_as_uint(x);
    return (unsigned short)((u + 0x7fffu + ((u >> 16) & 1u)) >> 16);
}
__device__ __forceinline__ float bf2f(unsigned short h) {
    return __uint_as_float((unsigned)h << 16);
}

#define ASYNC16(gp, lp) __builtin_amdgcn_global_load_lds( \
    (const __attribute__((address_space(1))) void*)(gp),  \
    (__attribute__((address_space(3))) void*)(lp), 16, 0, 0)

// ---------------------------------------------------------------------------
// Prep: codebook f32 -> hi/lo bf16 planes + e_sq. One wave per code row.
// ---------------------------------------------------------------------------
__global__ void vq_prep(const float* __restrict__ cb,
                        unsigned short* __restrict__ cb_hi,
                        unsigned short* __restrict__ cb_lo,
                        float* __restrict__ esq) {
    const int w = threadIdx.x >> 6, lane = threadIdx.x & 63;
    const int k = blockIdx.x * 4 + w;
    const float* row = cb + (size_t)k * D_DIM;
    unsigned short* hk = cb_hi + (size_t)k * D_DIM;
    unsigned short* lk = cb_lo + (size_t)k * D_DIM;
    float s = 0.f;
    for (int j = lane; j < D_DIM; j += 64) {
        float x = row[j];
        s = fmaf(x, x, s);
        unsigned short h = f2bf(x);
        hk[j] = h;
        lk[j] = f2bf(x - bf2f(h));
    }
    #pragma unroll
    for (int off = 32; off; off >>= 1) s += __shfl_down(s, off);
    if (!lane) esq[k] = s;
}

// ---------------------------------------------------------------------------
// MFMA distance kernel. 256 thr = 4 waves (2 code-halves x 2 token-halves).
// A = codes (M), B = tokens (N); D col=token(lane&15), row=code((lane>>4)*4+r).
// 3-product split-precision; per-token top2 written per (slice, code-half).
// ---------------------------------------------------------------------------
__launch_bounds__(256, 2)
__global__ void vq_dist_mfma(const float* __restrict__ token,
                             const unsigned short* __restrict__ cb_hi,
                             const unsigned short* __restrict__ cb_lo,
                             const float* __restrict__ esq,
                             float4* __restrict__ top2) {
    __shared__ unsigned short sAh[BCODE][BK];   // codes hi
    __shared__ unsigned short sAl[BCODE][BK];   // codes lo
    __shared__ unsigned short sBh[BTOK][BK];    // tokens hi
    __shared__ unsigned short sBl[BTOK][BK];    // tokens lo
    __shared__ float esq_s[SLICE];

    const int tid  = threadIdx.x;
    const int lane = tid & 63;
    const int w    = tid >> 6;
    const int tokBase    = blockIdx.x * BTOK;
    const int kSliceBase = blockIdx.y * SLICE;

    for (int j = tid; j < SLICE; j += 256) esq_s[j] = esq[kSliceBase + j];

    const int wc = (w >> 1) * 64;    // wave code offset
    const int wt = (w & 1) * 64;     // wave token offset
    const int lm = lane & 15;
    const int lk = (lane >> 4) * 8;  // k offset of this lane's frag slice

    float rm1[4], rm2[4];
    int   rk1[4], rk2[4];
    #pragma unroll
    for (int j = 0; j < 4; ++j) {
        rm1[j] = 3.4e38f; rm2[j] = 3.4e38f;
        rk1[j] = 0x7fffffff; rk2[j] = 0x7fffffff;
    }

    for (int ct = 0; ct < NCT; ++ct) {
        const int codeBase = kSliceBase + ct * BCODE;   // global code of tile row 0

        f32x4 acc[4][4];
        #pragma unroll
        for (int i = 0; i < 4; ++i)
            #pragma unroll
            for (int j = 0; j < 4; ++j) acc[i][j] = (f32x4){0.f, 0.f, 0.f, 0.f};

        for (int dc = 0; dc < D_DIM; dc += BK) {
            __syncthreads();
            // --- token tile: 1024 float4, 4 per thread ---
            float4 tv[4];
            #pragma unroll
            for (int j = 0; j < 4; ++j) {
                const int idx = j * 256 + tid;
                const int r = idx >> 3, c4 = idx & 7;
                tv[j] = *(const float4*)(token + (size_t)(tokBase + r) * D_DIM + dc + c4 * 4);
            }
            // --- codebook planes: async global->LDS, 16B per lane ---
            #pragma unroll
            for (int q = 0; q < 2; ++q) {
                const int i = w * 128 + q * 64 + lane;
                const int r = i >> 2, seg = i & 3;
                const size_t goff = (size_t)(codeBase + r) * D_DIM + dc + seg * 8;
                ASYNC16(cb_hi + goff, (char*)&sAh[0][0] + i * 16);
                ASYNC16(cb_lo + goff, (char*)&sAl[0][0] + i * 16);
            }
            // --- convert tokens, write hi/lo to LDS ---
            #pragma unroll
            for (int j = 0; j < 4; ++j) {
                const int idx = j * 256 + tid;
                const int r = idx >> 3, c4 = idx & 7;
                const unsigned short h0 = f2bf(tv[j].x), h1 = f2bf(tv[j].y),
                                     h2 = f2bf(tv[j].z), h3 = f2bf(tv[j].w);
                const unsigned short l0 = f2bf(tv[j].x - bf2f(h0)),
                                     l1 = f2bf(tv[j].y - bf2f(h1)),
                                     l2 = f2bf(tv[j].z - bf2f(h2)),
                                     l3 = f2bf(tv[j].w - bf2f(h3));
                uint2 ph, pl;
                ph.x = (unsigned)h0 | ((unsigned)h1 << 16);
                ph.y = (unsigned)h2 | ((unsigned)h3 << 16);
                pl.x = (unsigned)l0 | ((unsigned)l1 << 16);
                pl.y = (unsigned)l2 | ((unsigned)l3 << 16);
                *(uint2*)&sBh[r][c4 * 4] = ph;
                *(uint2*)&sBl[r][c4 * 4] = pl;
            }
            __syncthreads();   // compiler drains vmcnt (global_load_lds) + lgkm here

            bf16x8 ah[4], al[4], bh[4], bl[4];
            #pragma unroll
            for (int i = 0; i < 4; ++i) {
                ah[i] = *(const bf16x8*)&sAh[wc + i * 16 + lm][lk];
                al[i] = *(const bf16x8*)&sAl[wc + i * 16 + lm][lk];
            }
            #pragma unroll
            for (int j = 0; j < 4; ++j) {
                bh[j] = *(const bf16x8*)&sBh[wt + j * 16 + lm][lk];
                bl[j] = *(const bf16x8*)&sBl[wt + j * 16 + lm][lk];
            }
            #pragma unroll
            for (int i = 0; i < 4; ++i)
                #pragma unroll
                for (int j = 0; j < 4; ++j) {
                    acc[i][j] = __builtin_amdgcn_mfma_f32_16x16x32_bf16(ah[i], bh[j], acc[i][j], 0, 0, 0);
                    acc[i][j] = __builtin_amdgcn_mfma_f32_16x16x32_bf16(ah[i], bl[j], acc[i][j], 0, 0, 0);
                    acc[i][j] = __builtin_amdgcn_mfma_f32_16x16x32_bf16(al[i], bh[j], acc[i][j], 0, 0, 0);
                }
        }

        // epilogue: fold this tile into per-lane running top2 (ascending k scan)
        #pragma unroll
        for (int j = 0; j < 4; ++j)
            #pragma unroll
            for (int i = 0; i < 4; ++i)
                #pragma unroll
                for (int r = 0; r < 4; ++r) {
                    const int cl = ct * BCODE + wc + i * 16 + (lane >> 4) * 4 + r;
                    const float s = esq_s[cl] - 2.0f * acc[i][j][r];
                    const int kg = kSliceBase + cl;
                    if (s < rm1[j]) {
                        rm2[j] = rm1[j]; rk2[j] = rk1[j];
                        rm1[j] = s;      rk1[j] = kg;
                    } else if (s < rm2[j]) {
                        rm2[j] = s; rk2[j] = kg;
                    }
                }
    }

    // cross-lane top2 merge over the 4 k-groups (xor 16, 32), then write
    #pragma unroll
    for (int j = 0; j < 4; ++j) {
        float m1 = rm1[j], m2 = rm2[j];
        int   k1 = rk1[j], k2 = rk2[j];
        #pragma unroll
        for (int off = 16; off <= 32; off <<= 1) {
            const float om1 = __shfl_xor(m1, off); const int ok1 = __shfl_xor(k1, off);
            const float om2 = __shfl_xor(m2, off); const int ok2 = __shfl_xor(k2, off);
            const bool aB = (m1 < om1) || (m1 == om1 && k1 < ok1);
            float n1m, n2m; int n1k, n2k;
            if (aB) {
                n1m = m1; n1k = k1;
                const bool t = (om1 < m2) || (om1 == m2 && ok1 < k2);
                n2m = t ? om1 : m2; n2k = t ? ok1 : k2;
            } else {
                n1m = om1; n1k = ok1;
                const bool t = (m1 < om2) || (m1 == om2 && k1 < ok2);
                n2m = t ? m1 : om2; n2k = t ? k1 : ok2;
            }
            m1 = n1m; k1 = n1k; m2 = n2m; k2 = n2k;
        }
        if (lane < 16) {
            const int t = tokBase + wt + j * 16 + lane;
            const int slot = blockIdx.y * 2 + (w >> 1);
            top2[(size_t)t * NSLOT + slot] =
                make_float4(m1, __int_as_float(k1), m2, __int_as_float(k2));
        }
    }
}

// ---------------------------------------------------------------------------
// Rescore: merge 8 top2 slots per token; exact fp32 check when gap <= EPS.
// One wave per token.
// ---------------------------------------------------------------------------
__global__ void vq_rescore(const float* __restrict__ token,
                           const float* __restrict__ cb,
                           const float* __restrict__ esq,
                           const float4* __restrict__ top2,
                           unsigned int* __restrict__ idx_out) {
    const int w = threadIdx.x >> 6, lane = threadIdx.x & 63;
    const int t = blockIdx.x * 4 + w;
    const float4* slots = top2 + (size_t)t * NSLOT;

    float4 s0 = slots[0];
    float m1 = s0.x, m2 = s0.z;
    int   k1 = __float_as_int(s0.y), k2 = __float_as_int(s0.w);
    #pragma unroll
    for (int s = 1; s < NSLOT; ++s) {
        const float4 sv = slots[s];
        const float om1 = sv.x, om2 = sv.z;
        const int ok1 = __float_as_int(sv.y), ok2 = __float_as_int(sv.w);
        const bool aB = (m1 < om1) || (m1 == om1 && k1 < ok1);
        float n1m, n2m; int n1k, n2k;
        if (aB) {
            n1m = m1; n1k = k1;
            const bool c = (om1 < m2) || (om1 == m2 && ok1 < k2);
            n2m = c ? om1 : m2; n2k = c ? ok1 : k2;
        } else {
            n1m = om1; n1k = ok1;
            const bool c = (m1 < om2) || (m1 == om2 && k1 < ok2);
            n2m = c ? m1 : om2; n2k = c ? k1 : ok2;
        }
        m1 = n1m; k1 = n1k; m2 = n2m; k2 = n2k;
    }

    unsigned choice = (unsigned)k1;
    if (!(m2 - m1 > EPS)) {
        // exact fp32 rescore of both candidates
        const float* tr = token + (size_t)t * D_DIM;
        const float* c1 = cb + (size_t)k1 * D_DIM;
        const float* c2 = cb + (size_t)k2 * D_DIM;
        float d1 = 0.f, d2 = 0.f;
        for (int e = lane; e < D_DIM; e += 64) {
            const float x = tr[e];
            d1 = fmaf(c1[e], x, d1);
            d2 = fmaf(c2[e], x, d2);
        }
        #pragma unroll
        for (int off = 32; off; off >>= 1) {
            d1 += __shfl_down(d1, off);
            d2 += __shfl_down(d2, off);
        }
        d1 = __shfl(d1, 0);
        d2 = __shfl(d2, 0);
        const float s1 = esq[k1] - 2.f * d1;
        const float s2 = esq[k2] - 2.f * d2;
        if (s2 < s1 || (s2 == s1 && k2 < k1)) choice = (unsigned)k2;
    }
    if (!lane) idx_out[t] = choice;
}

// ---------------------------------------------------------------------------
// Gather: quantized rows, indices (as float), commit loss.
// ---------------------------------------------------------------------------
__global__ void vq_gather(const float* __restrict__ token,
                          const float* __restrict__ cb,
                          const unsigned int* __restrict__ idx_in,
                          float* __restrict__ out_q,
                          float* __restrict__ out_idx,
                          float* __restrict__ out_loss) {
    const int gid = blockIdx.x * blockDim.x + threadIdx.x;
    const int nthreads = gridDim.x * blockDim.x;
    const int N4 = (M_TOK * D_DIM) / 4;    // 192 float4 per row
    float lsum = 0.f;
    for (int i = gid; i < N4; i += nthreads) {
        const int t  = i / 192;
        const int c4 = (i - t * 192) * 4;
        const int idx = (int)idx_in[t];
        const float4 q = *(const float4*)(cb + (size_t)idx * D_DIM + c4);
        const float4 x = *(const float4*)(token + (size_t)t * D_DIM + c4);
        const float dx = q.x - x.x, dy = q.y - x.y, dz = q.z - x.z, dw = q.w - x.w;
        lsum += dx * dx + dy * dy + dz * dz + dw * dw;
        *(float4*)(out_q + (size_t)t * D_DIM + c4) = q;
    }
    if (gid < M_TOK) out_idx[gid] = (float)idx_in[gid];

    #pragma unroll
    for (int off = 32; off; off >>= 1) lsum += __shfl_down(lsum, off);
    __shared__ float ws[4];
    const int lane = threadIdx.x & 63, wid = threadIdx.x >> 6;
    if (lane == 0) ws[wid] = lsum;
    __syncthreads();
    if (threadIdx.x == 0)
        atomicAdd(out_loss, (ws[0] + ws[1] + ws[2] + ws[3]) *
                            (1.0f / (float)((size_t)M_TOK * D_DIM)));
}

// ---------------------------------------------------------------------------
extern "C" void kernel_launch(void* const* d_in, const int* in_sizes, int n_in,
                              void* d_out, int out_size, void* d_ws, size_t ws_size,
                              hipStream_t stream) {
    const float* token = (const float*)d_in[0];
    const float* cb    = (const float*)d_in[1];

    float* out_q    = (float*)d_out;
    float* out_idx  = out_q + (size_t)M_TOK * D_DIM;
    float* out_loss = out_idx + M_TOK;

    char* w = (char*)d_ws;
    unsigned short* cb_hi = (unsigned short*)(w);                 // 3,145,728 B
    unsigned short* cb_lo = (unsigned short*)(w + 3145728);       // 3,145,728 B
    float*          esq   = (float*)(w + 6291456);                // 8,192 B
    float4*         top2  = (float4*)(w + 6299648);               // 2,097,152 B
    unsigned int*   idxb  = (unsigned int*)(w + 8396800);         // 65,536 B

    hipMemsetAsync(out_loss, 0, sizeof(float), stream);

    vq_prep<<<K_CB / 4, 256, 0, stream>>>(cb, cb_hi, cb_lo, esq);

    dim3 g(M_TOK / BTOK, KSPLIT);
    vq_dist_mfma<<<g, 256, 0, stream>>>(token, cb_hi, cb_lo, esq, top2);

    vq_rescore<<<M_TOK / 4, 256, 0, stream>>>(token, cb, esq, top2, idxb);

    vq_gather<<<2048, 256, 0, stream>>>(token, cb, idxb,
                                        out_q, out_idx, out_loss);
}